// Round 1
// baseline (5295.621 us; speedup 1.0000x reference)
//
#include <hip/hip_runtime.h>
#include <cstdint>
#include <cstddef>

// ---------------- problem constants ----------------
#define DI 2048   // D_INNER
#define DM 1024   // DIM
#define BB 8      // batch
#define TT 1024   // seq len
#define ROWS (BB*TT)  // 8192

typedef short  short8 __attribute__((ext_vector_type(8)));
typedef float  f32x4  __attribute__((ext_vector_type(4)));

// ---------------- helpers ----------------
__device__ __forceinline__ unsigned short f2bf(float f) {
  unsigned int u = __builtin_bit_cast(unsigned int, f);
  u = u + 0x7fffu + ((u >> 16) & 1u);   // RNE
  return (unsigned short)(u >> 16);
}
__device__ __forceinline__ float fast_tanh(float x) {
  float ax = fabsf(x);
  float e  = __expf(-2.0f * ax);
  float t  = (1.0f - e) / (1.0f + e);
  return x < 0.0f ? -t : t;
}
__device__ __forceinline__ float silu_f(float z) {
  return z / (1.0f + __expf(-z));
}
__device__ __forceinline__ unsigned mulpk(unsigned a, unsigned b) {
  float a0 = __builtin_bit_cast(float, a << 16);
  float a1 = __builtin_bit_cast(float, a & 0xffff0000u);
  float b0 = __builtin_bit_cast(float, b << 16);
  float b1 = __builtin_bit_cast(float, b & 0xffff0000u);
  unsigned r0 = f2bf(a0 * b0), r1 = f2bf(a1 * b1);
  return r0 | (r1 << 16);
}
__device__ __forceinline__ uint4 pack8(const unsigned short* q) {
  uint4 p;
  p.x = (unsigned)q[0] | ((unsigned)q[1] << 16);
  p.y = (unsigned)q[2] | ((unsigned)q[3] << 16);
  p.z = (unsigned)q[4] | ((unsigned)q[5] << 16);
  p.w = (unsigned)q[6] | ((unsigned)q[7] << 16);
  return p;
}

// ---------------- f32 -> bf16 cast (4 elems/thread) ----------------
__global__ void cast_k(const float* __restrict__ s, short* __restrict__ d, int n4) {
  int i = blockIdx.x * 256 + threadIdx.x;
  if (i >= n4) return;
  float4 f = ((const float4*)s)[i];
  unsigned lo = (unsigned)f2bf(f.x) | ((unsigned)f2bf(f.y) << 16);
  unsigned hi = (unsigned)f2bf(f.z) | ((unsigned)f2bf(f.w) << 16);
  uint2 o; o.x = lo; o.y = hi;
  ((uint2*)d)[i] = o;
}

// ---------------- build circulant Bt for c_x: C[n][k] = c_x[(n-k) mod D] ----------------
__global__ void build_cx_k(const float* __restrict__ cx, short* __restrict__ C) {
  int tid = blockIdx.x * 256 + threadIdx.x;          // 0 .. 2048*256-1
  int n   = tid >> 8;
  int k0  = (tid & 255) * 8;
  unsigned short q[8];
#pragma unroll
  for (int j = 0; j < 8; ++j) q[j] = f2bf(cx[(n - (k0 + j)) & (DI - 1)]);
  *(uint4*)(C + (size_t)n * DI + k0) = pack8(q);
}

// ---------------- build A_ch in MFMA fragment order ----------------
// A[r][k] = c_h[(r-k) mod D], packed as frag(kt, lane): lane -> r=lane&15, G=lane>>4, k=32kt+8G+j
__global__ void build_ach_k(const float* __restrict__ ch, short* __restrict__ A) {
  int tid = blockIdx.x * 256 + threadIdx.x;          // 0..4095
  int kt = tid >> 6, Lw = tid & 63;
  int r = Lw & 15, G = Lw >> 4;
  unsigned short q[8];
#pragma unroll
  for (int j = 0; j < 8; ++j) {
    int k = 32 * kt + 8 * G + j;
    q[j] = f2bf(ch[(r - k) & (DI - 1)]);
  }
  *(uint4*)(A + (size_t)tid * 8) = pack8(q);
}

// ---------------- generic bf16 MFMA GEMM: C[M,N] = A[M,K] * Bt[N,K]^T ----------------
// mode 0: bf16 out; 1: f32 out + bias; 2: bf16 out + bias + silu; 3: f32 out
__global__ __launch_bounds__(256) void gemm_k(
    const short* __restrict__ A, const short* __restrict__ Bt,
    int M, int N, int K, int mode, const float* __restrict__ bias,
    float* __restrict__ outF, short* __restrict__ outH)
{
  __shared__ __align__(16) short As[128 * 40];
  __shared__ __align__(16) short Bs[128 * 40];
  const int tid  = threadIdx.x;
  const int m0   = blockIdx.y * 128, n0 = blockIdx.x * 128;
  const int wave = tid >> 6, lane = tid & 63;
  const int wy = wave >> 1, wx = wave & 1;
  const int l = lane & 15, G = lane >> 4;
  const int srow = tid >> 1, sseg = tid & 1;

  f32x4 acc[4][4];
#pragma unroll
  for (int i = 0; i < 4; ++i)
#pragma unroll
    for (int j = 0; j < 4; ++j) acc[i][j] = (f32x4){0.f, 0.f, 0.f, 0.f};

  for (int k0 = 0; k0 < K; k0 += 32) {
    if (k0) __syncthreads();
    const short* ga = A  + (size_t)(m0 + srow) * K + k0 + sseg * 16;
    const short* gb = Bt + (size_t)(n0 + srow) * K + k0 + sseg * 16;
    uint4 a0 = *(const uint4*)ga;
    uint4 a1 = *(const uint4*)(ga + 8);
    uint4 b0 = *(const uint4*)gb;
    uint4 b1 = *(const uint4*)(gb + 8);
    *(uint4*)&As[srow * 40 + sseg * 16]     = a0;
    *(uint4*)&As[srow * 40 + sseg * 16 + 8] = a1;
    *(uint4*)&Bs[srow * 40 + sseg * 16]     = b0;
    *(uint4*)&Bs[srow * 40 + sseg * 16 + 8] = b1;
    __syncthreads();
    short8 af[4], bfv[4];
#pragma unroll
    for (int i = 0; i < 4; ++i) af[i]  = *(const short8*)&As[(64 * wy + 16 * i + l) * 40 + 8 * G];
#pragma unroll
    for (int j = 0; j < 4; ++j) bfv[j] = *(const short8*)&Bs[(64 * wx + 16 * j + l) * 40 + 8 * G];
#pragma unroll
    for (int i = 0; i < 4; ++i)
#pragma unroll
      for (int j = 0; j < 4; ++j)
        acc[i][j] = __builtin_amdgcn_mfma_f32_16x16x32_bf16(af[i], bfv[j], acc[i][j], 0, 0, 0);
  }

#pragma unroll
  for (int j = 0; j < 4; ++j) {
    const int c = n0 + 64 * wx + 16 * j + l;
    float bv = 0.f;
    if (mode == 1 || mode == 2) bv = bias[c];
#pragma unroll
    for (int i = 0; i < 4; ++i) {
      const int r0 = m0 + 64 * wy + 16 * i + 4 * G;
#pragma unroll
      for (int v = 0; v < 4; ++v) {
        float z = acc[i][j][v] + bv;
        size_t off = (size_t)(r0 + v) * N + c;
        if (mode == 0)      outH[off] = (short)f2bf(z);
        else if (mode == 2) outH[off] = (short)f2bf(silu_f(z));
        else                outF[off] = z;
      }
    }
  }
}

// ---------------- sequential scan: one WG per batch, 1024 steps ----------------
// conv[n] = sum_m c_h[m] h[(n-m) mod D];  n = r + 16q; D[r][q] = A[r,k']*B[k',q],
// A static (prepacked frag-order, global), B[k',q] = h[(k'+16q) mod D] read from LDS.
__global__ __launch_bounds__(256) void scan_k(
    const float* __restrict__ pre, const float* __restrict__ h0,
    const short* __restrict__ Ach, short* __restrict__ hseq,
    float* __restrict__ hfin)
{
  __shared__ __align__(16) short h_lds[DI];
  __shared__ __align__(16) float pre_lds[2][DI];
  const int b = blockIdx.x;
  const int tid = threadIdx.x;
  const int wave = tid >> 6, lane = tid & 63;
  const int l = lane & 15, G = lane >> 4;
  const int nt0 = wave * 2;
  const float* preB = pre + (size_t)b * TT * DI;

  // init h from h0 (bf16, block-swizzled LDS layout)
  {
    const int blk = tid;                       // 8-elem block, 256 blocks
    const int pblk = blk ^ ((blk >> 3) & 7);
    unsigned short q[8];
#pragma unroll
    for (int j = 0; j < 8; ++j) q[j] = f2bf(h0[b * DI + blk * 8 + j]);
    *(uint4*)&h_lds[pblk * 8] = pack8(q);
  }
  // prefill pre[0] (strided: conflict-free LDS writes)
#pragma unroll
  for (int i = 0; i < 8; ++i) pre_lds[0][tid + 256 * i] = preB[tid + 256 * i];
  __syncthreads();

  const int base0 = G + 32 * nt0 + 2 * l;
  const short8* Ap = ((const short8*)Ach) + lane;

  for (int t = 0; t < TT; ++t) {
    const int cur = t & 1, nxt = cur ^ 1;
    // prefetch next pre row into regs (consumed after barrier1)
    float pf[8];
    {
      const float* pn = preB + (size_t)(t + 1 < TT ? t + 1 : TT - 1) * DI;
#pragma unroll
      for (int i = 0; i < 8; ++i) pf[i] = pn[tid + 256 * i];
    }
    f32x4 acc0 = {0.f, 0.f, 0.f, 0.f}, acc1 = {0.f, 0.f, 0.f, 0.f};
#pragma unroll 4
    for (int kt = 0; kt < 64; ++kt) {
      short8 av = Ap[kt * 64];                 // static A frag, L1-resident
      int sb0 = (base0 + 4 * kt) & 255;       sb0 ^= (sb0 >> 3) & 7;
      int sb1 = (base0 + 32 + 4 * kt) & 255;  sb1 ^= (sb1 >> 3) & 7;
      short8 bv0 = *(const short8*)&h_lds[sb0 * 8];
      short8 bv1 = *(const short8*)&h_lds[sb1 * 8];
      acc0 = __builtin_amdgcn_mfma_f32_16x16x32_bf16(av, bv0, acc0, 0, 0, 0);
      acc1 = __builtin_amdgcn_mfma_f32_16x16x32_bf16(av, bv1, acc1, 0, 0, 0);
    }
    __syncthreads();   // barrier1: all B reads of h_{t-1} done
#pragma unroll
    for (int i = 0; i < 8; ++i) pre_lds[nxt][tid + 256 * i] = pf[i];
    // epilogue: z = conv + pre_t ; h_t = tanh(z)
#pragma unroll
    for (int e = 0; e < 2; ++e) {
      const int nt = nt0 + e;
      f32x4 a = e ? acc1 : acc0;
      const int nbase = 4 * G + 16 * l + 256 * nt;   // n for v=0..3 is nbase+v
      float z0 = a[0] + pre_lds[cur][nbase + 0];
      float z1 = a[1] + pre_lds[cur][nbase + 1];
      float z2 = a[2] + pre_lds[cur][nbase + 2];
      float z3 = a[3] + pre_lds[cur][nbase + 3];
      float t0 = fast_tanh(z0), t1 = fast_tanh(z1);
      float t2 = fast_tanh(z2), t3 = fast_tanh(z3);
      unsigned q0 = f2bf(t0), q1 = f2bf(t1), q2 = f2bf(t2), q3 = f2bf(t3);
      const int blk  = nbase >> 3;
      const int pblk = blk ^ ((blk >> 3) & 7);
      const int off  = pblk * 8 + (nbase & 7);       // (nbase&7) in {0,4} -> 4B aligned
      *(unsigned*)&h_lds[off]     = q0 | (q1 << 16);
      *(unsigned*)&h_lds[off + 2] = q2 | (q3 << 16);
      if (t == TT - 1) {
        hfin[b * DI + nbase + 0] = t0;
        hfin[b * DI + nbase + 1] = t1;
        hfin[b * DI + nbase + 2] = t2;
        hfin[b * DI + nbase + 3] = t3;
      }
    }
    __syncthreads();   // barrier2: h_t complete in LDS
    // coalesced h_seq dump (reads h_t; safe until barrier1 of t+1)
    {
      const int blk = tid;
      const int pblk = blk ^ ((blk >> 3) & 7);
      uint4 hv = *(const uint4*)&h_lds[pblk * 8];
      *(uint4*)(hseq + (size_t)(b * TT + t) * DI + blk * 8) = hv;
    }
  }
}

// ---------------- cell = h_seq * gate (bf16, 8 elems/thread) ----------------
__global__ void mul_k(const short* __restrict__ h, const short* __restrict__ g,
                      short* __restrict__ o, int n8) {
  int i = blockIdx.x * 256 + threadIdx.x;
  if (i >= n8) return;
  uint4 hv = ((const uint4*)h)[i];
  uint4 gv = ((const uint4*)g)[i];
  uint4 ov;
  ov.x = mulpk(hv.x, gv.x);
  ov.y = mulpk(hv.y, gv.y);
  ov.z = mulpk(hv.z, gv.z);
  ov.w = mulpk(hv.w, gv.w);
  ((uint4*)o)[i] = ov;
}

// ---------------- launch ----------------
extern "C" void kernel_launch(void* const* d_in, const int* in_sizes, int n_in,
                              void* d_out, int out_size, void* d_ws, size_t ws_size,
                              hipStream_t stream) {
  const float* x    = (const float*)d_in[0];   // [8,1024,1024]
  const float* h0   = (const float*)d_in[1];   // [8,2048]
  const float* win  = (const float*)d_in[2];   // [2048,1024]
  const float* wout = (const float*)d_in[3];   // [1024,2048]
  const float* ch   = (const float*)d_in[4];   // [2048]
  const float* cx   = (const float*)d_in[5];   // [2048]
  const float* bb   = (const float*)d_in[6];   // [2048]
  const float* wg   = (const float*)d_in[7];   // [2048,2048]
  const float* bg   = (const float*)d_in[8];   // [2048]
  float* out = (float*)d_out;                  // 8192*1024 output + 8*2048 h_final

  char* ws = (char*)d_ws;
  // liveness-packed workspace (total ~176.3 MB)
  short* o_xb    = (short*)(ws + 0);                      // x bf16      16.78 MB (dead after gemm1)
  short* o_win   = (short*)(ws + 16777216);               // 4.19 MB     (dead after gemm1)
  short* o_wg    = (short*)(ws + 20971520);               // 8.39 MB     (dead after gemm3)
  short* o_cx    = (short*)(ws + 29360128);               // 8.39 MB     (dead after gemm2)
  short* o_hseq  = (short*)(ws + 0);                      // 33.55 MB    (written by scan, after the above are dead)
  short* o_xproj = (short*)(ws + 37748736);               // 33.55 MB
  float* o_pre   = (float*)(ws + 71303168);               // 67.11 MB f32 (dead after scan)
  short* o_cell  = (short*)(ws + 71303168);               // reuse of o_pre region
  short* o_gate  = (short*)(ws + 138412032);              // 33.55 MB
  short* o_wout  = (short*)(ws + 171966464);              // 4.19 MB
  short* o_ach   = (short*)(ws + 176160768);              // 64 KB

  // 1) dtype conversions
  cast_k<<<8192, 256, 0, stream>>>(x,    o_xb,   (BB * TT * DM) / 4);
  cast_k<<<2048, 256, 0, stream>>>(win,  o_win,  (DI * DM) / 4);
  cast_k<<<4096, 256, 0, stream>>>(wg,   o_wg,   (DI * DI) / 4);
  cast_k<<<2048, 256, 0, stream>>>(wout, o_wout, (DM * DI) / 4);
  build_cx_k<<<2048, 256, 0, stream>>>(cx, o_cx);
  build_ach_k<<<16, 256, 0, stream>>>(ch, o_ach);

  // 2) x_proj = x @ in_proj_w^T   [8192,2048] bf16
  gemm_k<<<dim3(DI / 128, ROWS / 128), 256, 0, stream>>>(
      o_xb, o_win, ROWS, DI, DM, 0, nullptr, nullptr, o_xproj);

  // 3) pre = circ(c_x) x_proj + b   [8192,2048] f32
  gemm_k<<<dim3(DI / 128, ROWS / 128), 256, 0, stream>>>(
      o_xproj, o_cx, ROWS, DI, DI, 1, bb, o_pre, nullptr);

  // 4) gate = silu(x_proj @ W_gate^T + b_gate)   [8192,2048] bf16
  gemm_k<<<dim3(DI / 128, ROWS / 128), 256, 0, stream>>>(
      o_xproj, o_wg, ROWS, DI, DI, 2, bg, nullptr, o_gate);

  // 5) recurrent scan: h_seq bf16 + h_final f32 (d_out tail)
  scan_k<<<BB, 256, 0, stream>>>(o_pre, h0, o_ach, o_hseq, out + (size_t)BB * TT * DM);

  // 6) cell = h_seq * gate
  mul_k<<<8192, 256, 0, stream>>>(o_hseq, o_gate, o_cell, (BB * TT * DI) / 8);

  // 7) output = cell @ out_proj_w^T   [8192,1024] f32 -> d_out
  gemm_k<<<dim3(DM / 128, ROWS / 128), 256, 0, stream>>>(
      o_cell, o_wout, ROWS, DM, DI, 3, nullptr, out, nullptr);
}

// Round 2
// 2145.474 us; speedup vs baseline: 2.4683x; 2.4683x over previous
//
#include <hip/hip_runtime.h>
#include <cstdint>
#include <cstddef>

// ---------------- problem constants ----------------
#define DI 2048   // D_INNER
#define DM 1024   // DIM
#define BB 8      // batch
#define TT 1024   // seq len
#define ROWS (BB*TT)  // 8192

typedef short  short8 __attribute__((ext_vector_type(8)));
typedef float  f32x4  __attribute__((ext_vector_type(4)));
typedef float  f32x16 __attribute__((ext_vector_type(16)));

// ---------------- helpers ----------------
__device__ __forceinline__ unsigned short f2bf(float f) {
  unsigned int u = __builtin_bit_cast(unsigned int, f);
  u = u + 0x7fffu + ((u >> 16) & 1u);   // RNE
  return (unsigned short)(u >> 16);
}
__device__ __forceinline__ float fast_tanh(float x) {
  float ax = fabsf(x);
  float e  = __expf(-2.0f * ax);
  float t  = (1.0f - e) / (1.0f + e);
  return x < 0.0f ? -t : t;
}
__device__ __forceinline__ float silu_f(float z) {
  return z / (1.0f + __expf(-z));
}
__device__ __forceinline__ unsigned mulpk(unsigned a, unsigned b) {
  float a0 = __builtin_bit_cast(float, a << 16);
  float a1 = __builtin_bit_cast(float, a & 0xffff0000u);
  float b0 = __builtin_bit_cast(float, b << 16);
  float b1 = __builtin_bit_cast(float, b & 0xffff0000u);
  unsigned r0 = f2bf(a0 * b0), r1 = f2bf(a1 * b1);
  return r0 | (r1 << 16);
}
__device__ __forceinline__ uint4 pack8(const unsigned short* q) {
  uint4 p;
  p.x = (unsigned)q[0] | ((unsigned)q[1] << 16);
  p.y = (unsigned)q[2] | ((unsigned)q[3] << 16);
  p.z = (unsigned)q[4] | ((unsigned)q[5] << 16);
  p.w = (unsigned)q[6] | ((unsigned)q[7] << 16);
  return p;
}

// ---------------- f32 -> bf16 cast (4 elems/thread) ----------------
__global__ void cast_k(const float* __restrict__ s, short* __restrict__ d, int n4) {
  int i = blockIdx.x * 256 + threadIdx.x;
  if (i >= n4) return;
  float4 f = ((const float4*)s)[i];
  unsigned lo = (unsigned)f2bf(f.x) | ((unsigned)f2bf(f.y) << 16);
  unsigned hi = (unsigned)f2bf(f.z) | ((unsigned)f2bf(f.w) << 16);
  uint2 o; o.x = lo; o.y = hi;
  ((uint2*)d)[i] = o;
}

// ---------------- build circulant Bt for c_x: C[n][k] = c_x[(n-k) mod D] ----------------
__global__ void build_cx_k(const float* __restrict__ cx, short* __restrict__ C) {
  int tid = blockIdx.x * 256 + threadIdx.x;          // 0 .. 2048*256-1
  int n   = tid >> 8;
  int k0  = (tid & 255) * 8;
  unsigned short q[8];
#pragma unroll
  for (int j = 0; j < 8; ++j) q[j] = f2bf(cx[(n - (k0 + j)) & (DI - 1)]);
  *(uint4*)(C + (size_t)n * DI + k0) = pack8(q);
}

// ---------------- generic bf16 MFMA GEMM: C[M,N] = A[M,K] * Bt[N,K]^T ----------------
// A2 (optional): elementwise bf16 multiplier on A (fused cell = h*gate).
// mode 0: bf16 out; 1: f32 out + bias; 2: bf16 out + bias + silu; 3: f32 out
__global__ __launch_bounds__(256) void gemm_k(
    const short* __restrict__ A, const short* __restrict__ A2,
    const short* __restrict__ Bt,
    int M, int N, int K, int mode, const float* __restrict__ bias,
    float* __restrict__ outF, short* __restrict__ outH)
{
  __shared__ __align__(16) short As[128 * 40];
  __shared__ __align__(16) short Bs[128 * 40];
  const int tid  = threadIdx.x;
  const int m0   = blockIdx.y * 128, n0 = blockIdx.x * 128;
  const int wave = tid >> 6, lane = tid & 63;
  const int wy = wave >> 1, wx = wave & 1;
  const int l = lane & 15, G = lane >> 4;
  const int srow = tid >> 1, sseg = tid & 1;

  f32x4 acc[4][4];
#pragma unroll
  for (int i = 0; i < 4; ++i)
#pragma unroll
    for (int j = 0; j < 4; ++j) acc[i][j] = (f32x4){0.f, 0.f, 0.f, 0.f};

  for (int k0 = 0; k0 < K; k0 += 32) {
    if (k0) __syncthreads();
    const short* ga = A  + (size_t)(m0 + srow) * K + k0 + sseg * 16;
    const short* gb = Bt + (size_t)(n0 + srow) * K + k0 + sseg * 16;
    uint4 a0 = *(const uint4*)ga;
    uint4 a1 = *(const uint4*)(ga + 8);
    if (A2) {
      const short* g2 = A2 + (size_t)(m0 + srow) * K + k0 + sseg * 16;
      uint4 m0v = *(const uint4*)g2;
      uint4 m1v = *(const uint4*)(g2 + 8);
      a0.x = mulpk(a0.x, m0v.x); a0.y = mulpk(a0.y, m0v.y);
      a0.z = mulpk(a0.z, m0v.z); a0.w = mulpk(a0.w, m0v.w);
      a1.x = mulpk(a1.x, m1v.x); a1.y = mulpk(a1.y, m1v.y);
      a1.z = mulpk(a1.z, m1v.z); a1.w = mulpk(a1.w, m1v.w);
    }
    uint4 b0 = *(const uint4*)gb;
    uint4 b1 = *(const uint4*)(gb + 8);
    *(uint4*)&As[srow * 40 + sseg * 16]     = a0;
    *(uint4*)&As[srow * 40 + sseg * 16 + 8] = a1;
    *(uint4*)&Bs[srow * 40 + sseg * 16]     = b0;
    *(uint4*)&Bs[srow * 40 + sseg * 16 + 8] = b1;
    __syncthreads();
    short8 af[4], bfv[4];
#pragma unroll
    for (int i = 0; i < 4; ++i) af[i]  = *(const short8*)&As[(64 * wy + 16 * i + l) * 40 + 8 * G];
#pragma unroll
    for (int j = 0; j < 4; ++j) bfv[j] = *(const short8*)&Bs[(64 * wx + 16 * j + l) * 40 + 8 * G];
#pragma unroll
    for (int i = 0; i < 4; ++i)
#pragma unroll
      for (int j = 0; j < 4; ++j)
        acc[i][j] = __builtin_amdgcn_mfma_f32_16x16x32_bf16(af[i], bfv[j], acc[i][j], 0, 0, 0);
  }

#pragma unroll
  for (int j = 0; j < 4; ++j) {
    const int c = n0 + 64 * wx + 16 * j + l;
    float bv = 0.f;
    if (mode == 1 || mode == 2) bv = bias[c];
#pragma unroll
    for (int i = 0; i < 4; ++i) {
      const int r0 = m0 + 64 * wy + 16 * i + 4 * G;
#pragma unroll
      for (int v = 0; v < 4; ++v) {
        float z = acc[i][j][v] + bv;
        size_t off = (size_t)(r0 + v) * N + c;
        if (mode == 0)      outH[off] = (short)f2bf(z);
        else if (mode == 2) outH[off] = (short)f2bf(silu_f(z));
        else                outF[off] = z;
      }
    }
  }
}

// ---------------- fused: scan (blocks 0..7) + gate GEMM (blocks 8..255) ----------------
// Scan: 32x32x16 MFMA formulation. n = m + 32q, m in [0,32), q in [0,64).
//   A[m][k] = c_h[(m-k) mod D]  (static -> held in registers, 128 VGPR/lane)
//   B[k][q] = h[(k+32q) mod D]  (read from swizzled LDS copy of h)
// 8 waves: nh = wid&1 (q-half), kg = wid>>1 (K quarter). K-split partials
// reduced through LDS. 2 barriers/step.
__global__ __launch_bounds__(512, 2) void fused_k(
    const float* __restrict__ pre, const float* __restrict__ h0,
    const float* __restrict__ ch, short* __restrict__ hseq,
    float* __restrict__ hfin,
    const short* __restrict__ xproj, const short* __restrict__ wg,
    const float* __restrict__ bg, short* __restrict__ gate)
{
  __shared__ __align__(16) char smem[53248];   // scan: 4K h + 16K pre(2x) + 32K part
  const int bid = blockIdx.x;
  const int tid = threadIdx.x;

  if (bid < BB) {
    // ================= scan path =================
    short* h_lds   = (short*)smem;             // 2048 bf16 (swizzled 8-elem blocks)
    float* pre_lds = (float*)(smem + 4096);    // 2 x 2048 f32
    float* part    = (float*)(smem + 20480);   // 4 x 2048 f32
    const int b = bid;
    const int wid = tid >> 6, lane = tid & 63;
    const int nh = wid & 1, kg = wid >> 1;     // q-half, K-quarter
    const int L = lane & 31, G2 = lane >> 5;
    const int q = 32 * nh + L;
    const float* preB = pre + (size_t)b * TT * DI;

    // A fragments: av[i][j] = c_h[(L - (16*(32kg+i) + 8*G2 + j)) mod D]
    short8 av[32];
#pragma unroll
    for (int i = 0; i < 32; ++i) {
      const int kbase = 16 * (32 * kg + i) + 8 * G2;
      short8 v;
#pragma unroll
      for (int j = 0; j < 8; ++j)
        v[j] = (short)f2bf(ch[(L - kbase - j) & (DI - 1)]);
      av[i] = v;
    }

    // init h_lds (swizzled) + pre_lds[0]
    {
      const int n0 = 4 * tid;
      float4 hv = *(const float4*)(h0 + b * DI + n0);
      unsigned lo = (unsigned)f2bf(hv.x) | ((unsigned)f2bf(hv.y) << 16);
      unsigned hi = (unsigned)f2bf(hv.z) | ((unsigned)f2bf(hv.w) << 16);
      const int blk = tid >> 1;
      const int pblk = blk ^ ((blk >> 3) & 7);
      uint2 w; w.x = lo; w.y = hi;
      *(uint2*)&h_lds[pblk * 8 + 4 * (tid & 1)] = w;
      *(float4*)&pre_lds[n0] = *(const float4*)(preB + n0);
    }
    __syncthreads();

    const int cbase = (G2 + 4 * q + 64 * kg) & 255;   // B-frag 8-elem block base

    for (int t = 0; t < TT; ++t) {
      const int cur = t & 1;
      // prefetch next pre row (consumed after barrier A)
      const float* pn = preB + (size_t)(t + 1 < TT ? t + 1 : t) * DI;
      float4 pf = *(const float4*)(pn + 4 * tid);

      f32x16 acc0, acc1;
#pragma unroll
      for (int v = 0; v < 16; ++v) { acc0[v] = 0.f; acc1[v] = 0.f; }
#pragma unroll
      for (int i = 0; i < 32; i += 2) {
        int blkA = (cbase + 2 * i) & 255;
        int blkB = (cbase + 2 * i + 2) & 255;
        int pA = blkA ^ ((blkA >> 3) & 7);
        int pB = blkB ^ ((blkB >> 3) & 7);
        short8 bvA = *(const short8*)&h_lds[pA * 8];
        short8 bvB = *(const short8*)&h_lds[pB * 8];
        acc0 = __builtin_amdgcn_mfma_f32_32x32x16_bf16(av[i],     bvA, acc0, 0, 0, 0);
        acc1 = __builtin_amdgcn_mfma_f32_32x32x16_bf16(av[i + 1], bvB, acc1, 0, 0, 0);
      }
      // partial write (swizzled f32x4 blocks) + pre double-buffer fill
      {
        float* pk = part + kg * DI;
#pragma unroll
        for (int s = 0; s < 4; ++s) {
          const int blk4 = 2 * s + G2 + 8 * q;        // n>>2, n = 8s+4G2+32q
          const int p4 = blk4 ^ ((blk4 >> 3) & 7);
          float4 w;
          w.x = acc0[4 * s + 0] + acc1[4 * s + 0];
          w.y = acc0[4 * s + 1] + acc1[4 * s + 1];
          w.z = acc0[4 * s + 2] + acc1[4 * s + 2];
          w.w = acc0[4 * s + 3] + acc1[4 * s + 3];
          *(float4*)&pk[4 * p4] = w;
        }
        *(float4*)&pre_lds[(cur ^ 1) * DI + 4 * tid] = pf;
      }
      __syncthreads();   // barrier A: partials + next-pre visible
      // epilogue: reduce 4 partials, add pre, tanh, write h + hseq
      {
        const int pb = tid ^ ((tid >> 3) & 7);
        float4 c0 = *(const float4*)&part[4 * pb];
        float4 c1 = *(const float4*)&part[DI + 4 * pb];
        float4 c2 = *(const float4*)&part[2 * DI + 4 * pb];
        float4 c3 = *(const float4*)&part[3 * DI + 4 * pb];
        float4 pr = *(const float4*)&pre_lds[cur * DI + 4 * tid];
        float z0 = c0.x + c1.x + c2.x + c3.x + pr.x;
        float z1 = c0.y + c1.y + c2.y + c3.y + pr.y;
        float z2 = c0.z + c1.z + c2.z + c3.z + pr.z;
        float z3 = c0.w + c1.w + c2.w + c3.w + pr.w;
        float t0 = fast_tanh(z0), t1 = fast_tanh(z1);
        float t2 = fast_tanh(z2), t3 = fast_tanh(z3);
        unsigned lo = (unsigned)f2bf(t0) | ((unsigned)f2bf(t1) << 16);
        unsigned hi = (unsigned)f2bf(t2) | ((unsigned)f2bf(t3) << 16);
        const int blk = tid >> 1;
        const int pblk = blk ^ ((blk >> 3) & 7);
        uint2 w; w.x = lo; w.y = hi;
        *(uint2*)&h_lds[pblk * 8 + 4 * (tid & 1)] = w;
        *(uint2*)(hseq + (size_t)(b * TT + t) * DI + 4 * tid) = w;
        if (t == TT - 1) {
          float4 hf; hf.x = t0; hf.y = t1; hf.z = t2; hf.w = t3;
          *(float4*)(hfin + b * DI + 4 * tid) = hf;
        }
      }
      __syncthreads();   // barrier B: h_t complete before next step's B reads
    }
  } else {
    // ================= gate GEMM path (persistent tiles) =================
    // tile = 256 rows x 128 cols; 8 waves: wy in [0,4), wx in [0,2)
    short* As = (short*)smem;              // 256 x 40
    short* Bs = (short*)(smem + 20480);    // 128 x 40
    const int wid = tid >> 6, lane = tid & 63;
    const int wy = wid >> 1, wx = wid & 1;
    const int l = lane & 15, G = lane >> 4;

    for (int tile = bid - BB; tile < 512; tile += 248) {
      const int m0 = (tile & 31) * 256, n0 = (tile >> 5) * 128;
      f32x4 acc[4][4];
#pragma unroll
      for (int i = 0; i < 4; ++i)
#pragma unroll
        for (int j = 0; j < 4; ++j) acc[i][j] = (f32x4){0.f, 0.f, 0.f, 0.f};

      for (int k0 = 0; k0 < DI; k0 += 32) {
        __syncthreads();
        const short* ga = xproj + (size_t)(m0 + (tid >> 1)) * DI + k0 + (tid & 1) * 16;
        const short* gb = wg    + (size_t)(n0 + (tid >> 2)) * DI + k0 + (tid & 3) * 8;
        uint4 a0 = *(const uint4*)ga;
        uint4 a1 = *(const uint4*)(ga + 8);
        uint4 b0 = *(const uint4*)gb;
        *(uint4*)&As[(tid >> 1) * 40 + (tid & 1) * 16]     = a0;
        *(uint4*)&As[(tid >> 1) * 40 + (tid & 1) * 16 + 8] = a1;
        *(uint4*)&Bs[(tid >> 2) * 40 + (tid & 3) * 8]      = b0;
        __syncthreads();
        short8 af[4], bfv[4];
#pragma unroll
        for (int i = 0; i < 4; ++i) af[i]  = *(const short8*)&As[(64 * wy + 16 * i + l) * 40 + 8 * G];
#pragma unroll
        for (int j = 0; j < 4; ++j) bfv[j] = *(const short8*)&Bs[(64 * wx + 16 * j + l) * 40 + 8 * G];
#pragma unroll
        for (int i = 0; i < 4; ++i)
#pragma unroll
          for (int j = 0; j < 4; ++j)
            acc[i][j] = __builtin_amdgcn_mfma_f32_16x16x32_bf16(af[i], bfv[j], acc[i][j], 0, 0, 0);
      }
#pragma unroll
      for (int j = 0; j < 4; ++j) {
        const int c = n0 + 64 * wx + 16 * j + l;
        const float bv = bg[c];
#pragma unroll
        for (int i = 0; i < 4; ++i) {
          const int r0 = m0 + 64 * wy + 16 * i + 4 * G;
#pragma unroll
          for (int v = 0; v < 4; ++v) {
            float z = acc[i][j][v] + bv;
            gate[(size_t)(r0 + v) * DI + c] = (short)f2bf(silu_f(z));
          }
        }
      }
      __syncthreads();   // protect LDS before next tile's staging
    }
  }
}

// ---------------- launch ----------------
extern "C" void kernel_launch(void* const* d_in, const int* in_sizes, int n_in,
                              void* d_out, int out_size, void* d_ws, size_t ws_size,
                              hipStream_t stream) {
  const float* x    = (const float*)d_in[0];   // [8,1024,1024]
  const float* h0   = (const float*)d_in[1];   // [8,2048]
  const float* win  = (const float*)d_in[2];   // [2048,1024]
  const float* wout = (const float*)d_in[3];   // [1024,2048]
  const float* ch   = (const float*)d_in[4];   // [2048]
  const float* cx   = (const float*)d_in[5];   // [2048]
  const float* bb   = (const float*)d_in[6];   // [2048]
  const float* wg   = (const float*)d_in[7];   // [2048,2048]
  const float* bg   = (const float*)d_in[8];   // [2048]
  float* out = (float*)d_out;                  // 8192*1024 output + 8*2048 h_final

  char* ws = (char*)d_ws;
  // liveness-packed workspace (peak 176,160,768 B)
  short* o_xb    = (short*)(ws + 0);           // 16.78M, dead after xproj gemm
  short* o_win   = (short*)(ws + 16777216);    // 4.19M,  dead after xproj gemm
  short* o_cx    = (short*)(ws + 20971520);    // 8.39M,  dead after pre gemm
  short* o_hseq  = (short*)(ws + 0);           // 33.55M, written by fused (above all dead)
  short* o_xproj = (short*)(ws + 33554432);    // 33.55M
  float* o_pre   = (float*)(ws + 67108864);    // 67.11M f32, dead after fused
  short* o_wout  = (short*)(ws + 67108864);    // 4.19M, cast AFTER fused (reuses pre)
  short* o_gate  = (short*)(ws + 134217728);   // 33.55M
  short* o_wg    = (short*)(ws + 167772160);   // 8.39M

  // 1) dtype conversions / circulant build
  cast_k<<<8192, 256, 0, stream>>>(x,   o_xb,  (BB * TT * DM) / 4);
  cast_k<<<2048, 256, 0, stream>>>(win, o_win, (DI * DM) / 4);
  cast_k<<<4096, 256, 0, stream>>>(wg,  o_wg,  (DI * DI) / 4);
  build_cx_k<<<2048, 256, 0, stream>>>(cx, o_cx);

  // 2) x_proj = x @ in_proj_w^T   [8192,2048] bf16
  gemm_k<<<dim3(DI / 128, ROWS / 128), 256, 0, stream>>>(
      o_xb, nullptr, o_win, ROWS, DI, DM, 0, nullptr, nullptr, o_xproj);

  // 3) pre = circ(c_x) x_proj + b   [8192,2048] f32
  gemm_k<<<dim3(DI / 128, ROWS / 128), 256, 0, stream>>>(
      o_xproj, nullptr, o_cx, ROWS, DI, DI, 1, bb, o_pre, nullptr);

  // 4) fused: scan (8 blocks) + gate GEMM (248 persistent blocks)
  fused_k<<<256, 512, 0, stream>>>(o_pre, h0, ch, o_hseq,
                                   out + (size_t)BB * TT * DM,
                                   o_xproj, o_wg, bg, o_gate);

  // 5) wout cast (into dead pre region)
  cast_k<<<2048, 256, 0, stream>>>(wout, o_wout, (DM * DI) / 4);

  // 6) output = (h_seq * gate) @ out_proj_w^T  — multiply fused into A-staging
  gemm_k<<<dim3(DM / 128, ROWS / 128), 256, 0, stream>>>(
      o_hseq, o_gate, o_wout, ROWS, DM, DI, 3, nullptr, out, nullptr);
}